// Round 1
// baseline (377.904 us; speedup 1.0000x reference)
//
#include <hip/hip_runtime.h>
#include <hip/hip_bf16.h>

typedef unsigned short u16;
typedef __attribute__((ext_vector_type(8))) __bf16 bf16x8;
typedef __attribute__((ext_vector_type(4))) float f32x4;

// dims
#define Bd  2048
#define Nd  768
#define Md  8192
#define Ed  512
#define Hd  8

__device__ __forceinline__ u16 f2bf(float f){
    union { float f; unsigned u; } a; a.f = f;
    unsigned r = a.u + 0x7fffu + ((a.u >> 16) & 1u);
    return (u16)(r >> 16);
}

__device__ __forceinline__ void glds16(const void* g, void* l){
    __builtin_amdgcn_global_load_lds((const __attribute__((address_space(1))) void*)g,
                                     (__attribute__((address_space(3))) void*)l, 16, 0, 0);
}

// ---------------- elementwise conversions ----------------
__global__ void cvt_bf16_k(const float* __restrict__ in, u16* __restrict__ out, int n){
    int i = (blockIdx.x*blockDim.x + threadIdx.x)*4;
    if (i >= n) return;
    float4 v = *(const float4*)(in + i);
    ushort4 u; u.x=f2bf(v.x); u.y=f2bf(v.y); u.z=f2bf(v.z); u.w=f2bf(v.w);
    *(ushort4*)(out + i) = u;
}

__global__ void cvt_copy_k(const float* __restrict__ in, u16* __restrict__ outb,
                           float* __restrict__ outf, int n){
    int i = (blockIdx.x*blockDim.x + threadIdx.x)*4;
    if (i >= n) return;
    float4 v = *(const float4*)(in + i);
    *(float4*)(outf + i) = v;
    ushort4 u; u.x=f2bf(v.x); u.y=f2bf(v.y); u.z=f2bf(v.z); u.w=f2bf(v.w);
    *(ushort4*)(outb + i) = u;
}

// transpose + convert: out[c*R + r] = bf16(in[r*C + c]);  R,C multiples of 32
__global__ void tcvt_k(const float* __restrict__ in, u16* __restrict__ out, int R, int C){
    __shared__ float t[32][33];
    const int tx = threadIdx.x & 31, ty = threadIdx.x >> 5;  // 256 threads
    const int r0 = blockIdx.y*32, c0 = blockIdx.x*32;
    #pragma unroll
    for (int i=0;i<4;i++)
        t[ty + i*8][tx] = in[(size_t)(r0+ty+i*8)*C + c0+tx];
    __syncthreads();
    #pragma unroll
    for (int i=0;i<4;i++)
        out[(size_t)(c0+ty+i*8)*R + r0+tx] = f2bf(t[tx][ty+i*8]);
}

// bo[i] = sum_j W_o_w[i,j]*out_b[j] + W_o_b[i]   (768 rows, K=512)
__global__ void gemv_bo_k(const float* __restrict__ W, const float* __restrict__ ob,
                          const float* __restrict__ wob, float* __restrict__ bo){
    const int wave = threadIdx.x >> 6, lane = threadIdx.x & 63;
    const int i = blockIdx.x*4 + wave;
    float s = 0.f;
    for (int j = lane; j < 512; j += 64) s += W[(size_t)i*512 + j] * ob[j];
    #pragma unroll
    for (int off = 32; off; off >>= 1) s += __shfl_down(s, off);
    if (lane == 0) bo[i] = s + wob[i];
}

__global__ void rinv_k(const float* __restrict__ se, float* __restrict__ r1, float* __restrict__ r8){
    int i = blockIdx.x*256 + threadIdx.x;   // 16384 total
    float v = se[i];
    r1[i] = 1.f / v;
    r8[i] = 0.125f / v;
}

// ---------------- generic GEMM: C[M,N] = alpha*A[M,K]@B[N,K]^T (+bias)  ----------------
// bf16 inputs, 128x128 tile, BK=64, 4 waves (2x2), m97-structure (linear LDS).
// BIASMODE: 0 none, 1 per-col, 2 per-row.  OUTF32: 1 -> float out, 0 -> bf16 out.
template<int BIASMODE, int OUTF32>
__global__ __launch_bounds__(256, 2)
void gemm_bt(const u16* __restrict__ A, const u16* __restrict__ B,
             void* __restrict__ C, const float* __restrict__ bias,
             int M, int N, int K, float alpha)
{
    __shared__ u16 lA[128*64];
    __shared__ u16 lB[128*64];
    const int tid = threadIdx.x;
    const int wave = tid >> 6, lane = tid & 63;
    const int wr = wave >> 1, wc = wave & 1;
    const size_t row0 = (size_t)blockIdx.y * 128;
    const size_t col0 = (size_t)blockIdx.x * 128;

    f32x4 acc[4][4] = {};

    const int srow = wave*32 + (lane>>3);
    const int scol = (lane&7)*8;
    const u16* gA = A + (row0 + srow)*(size_t)K + scol;
    const u16* gB = B + (col0 + srow)*(size_t)K + scol;

    for (int kt = 0; kt < K; kt += 64) {
        #pragma unroll
        for (int i = 0; i < 4; ++i) {
            glds16(gA + (size_t)i*8*K + kt, lA + (wave*32 + i*8)*64);
            glds16(gB + (size_t)i*8*K + kt, lB + (wave*32 + i*8)*64);
        }
        __syncthreads();
        #pragma unroll
        for (int ks = 0; ks < 2; ++ks) {
            bf16x8 af[4], bfv[4];
            #pragma unroll
            for (int i = 0; i < 4; ++i)
                af[i] = *(const bf16x8*)&lA[(wr*64 + i*16 + (lane&15))*64 + ks*32 + (lane>>4)*8];
            #pragma unroll
            for (int i = 0; i < 4; ++i)
                bfv[i] = *(const bf16x8*)&lB[(wc*64 + i*16 + (lane&15))*64 + ks*32 + (lane>>4)*8];
            #pragma unroll
            for (int mi = 0; mi < 4; ++mi)
                #pragma unroll
                for (int ni = 0; ni < 4; ++ni)
                    acc[mi][ni] = __builtin_amdgcn_mfma_f32_16x16x32_bf16(af[mi], bfv[ni], acc[mi][ni], 0, 0, 0);
        }
        __syncthreads();
    }

    #pragma unroll
    for (int mi = 0; mi < 4; ++mi) {
        #pragma unroll
        for (int j = 0; j < 4; ++j) {
            const size_t r = row0 + wr*64 + mi*16 + (lane>>4)*4 + j;
            float badd_r = (BIASMODE==2) ? bias[r] : 0.f;
            #pragma unroll
            for (int ni = 0; ni < 4; ++ni) {
                const size_t c = col0 + wc*64 + ni*16 + (lane&15);
                float v = acc[mi][ni][j] * alpha + ((BIASMODE==1) ? bias[c] : badd_r);
                if (OUTF32) ((float*)C)[r*(size_t)N + c] = v;
                else        ((u16*)C)[r*(size_t)N + c] = f2bf(v);
            }
        }
    }
}

// ---------------- attention pass 1: sumexp[h,b] = sum_m exp(0.125*q_hb . k_hm) ----------------
// grid (mslice=4, btile=16, h=8), 256 threads. XOR-swizzled LDS (both sides).
__global__ __launch_bounds__(256, 2)
void attn_stats(const u16* __restrict__ qp, const u16* __restrict__ kp,
                float* __restrict__ sumexp)
{
    __shared__ u16 lQ[128*64];
    __shared__ u16 lK[128*64];
    const int tid = threadIdx.x, wave = tid>>6, lane = tid&63;
    const int wr = wave>>1, wc = wave&1;
    const int msl = blockIdx.x, bt = blockIdx.y, h = blockIdx.z;

    #pragma unroll
    for (int i=0;i<4;i++){
        int rr = wave*32 + i*8 + (lane>>3);
        int cg = ((lane&7) ^ (rr&7))*8;
        glds16(qp + (size_t)(bt*128+rr)*512 + h*64 + cg, lQ + (wave*32+i*8)*64);
    }

    float rsum[4][4] = {};
    for (int mt = msl*16; mt < msl*16+16; ++mt){
        __syncthreads();
        #pragma unroll
        for (int i=0;i<4;i++){
            int rr = wave*32 + i*8 + (lane>>3);
            int cg = ((lane&7) ^ (rr&7))*8;
            glds16(kp + (size_t)(mt*128+rr)*512 + h*64 + cg, lK + (wave*32+i*8)*64);
        }
        __syncthreads();
        f32x4 acc[4][4] = {};
        #pragma unroll
        for (int ks=0;ks<2;++ks){
            bf16x8 af[4], bfv[4];
            #pragma unroll
            for (int i=0;i<4;i++){
                int ra = wr*64 + i*16 + (lane&15);
                af[i] = *(const bf16x8*)&lQ[ra*64 + (((ks*4+(lane>>4)) ^ (ra&7))<<3)];
            }
            #pragma unroll
            for (int i=0;i<4;i++){
                int rb = wc*64 + i*16 + (lane&15);
                bfv[i] = *(const bf16x8*)&lK[rb*64 + (((ks*4+(lane>>4)) ^ (rb&7))<<3)];
            }
            #pragma unroll
            for (int mi=0;mi<4;mi++)
                #pragma unroll
                for (int ni=0;ni<4;ni++)
                    acc[mi][ni] = __builtin_amdgcn_mfma_f32_16x16x32_bf16(af[mi], bfv[ni], acc[mi][ni],0,0,0);
        }
        #pragma unroll
        for (int mi=0;mi<4;mi++)
            #pragma unroll
            for (int ni=0;ni<4;ni++)
                #pragma unroll
                for (int j=0;j<4;j++)
                    rsum[mi][j] += __expf(0.125f*acc[mi][ni][j]);
    }
    #pragma unroll
    for (int mi=0;mi<4;mi++)
        #pragma unroll
        for (int j=0;j<4;j++){
            float s = rsum[mi][j];
            s += __shfl_xor(s, 1); s += __shfl_xor(s, 2);
            s += __shfl_xor(s, 4); s += __shfl_xor(s, 8);
            if ((lane&15)==0){
                int r = bt*128 + wr*64 + mi*16 + (lane>>4)*4 + j;
                atomicAdd(&sumexp[h*2048 + r], s);
            }
        }
}

// ---------------- attention pass 2: f[b,m] = sum_h exp(s_hbm)*rinv8[h,b] ----------------
// grid (mtile=64, btile=16), 256 threads.
__global__ __launch_bounds__(256, 2)
void attn_f(const u16* __restrict__ qp, const u16* __restrict__ kp,
            const float* __restrict__ rinv8, float* __restrict__ fo)
{
    __shared__ u16 lQ[128*64];
    __shared__ u16 lK[128*64];
    __shared__ float lR[8*128];
    const int tid = threadIdx.x, wave = tid>>6, lane = tid&63;
    const int wr = wave>>1, wc = wave&1;
    const int mt = blockIdx.x, bt = blockIdx.y;

    #pragma unroll
    for (int i=0;i<4;i++){
        int id = i*256 + tid;
        lR[id] = rinv8[(id>>7)*2048 + bt*128 + (id&127)];
    }

    float facc[4][4][4] = {};
    for (int h=0; h<8; ++h){
        __syncthreads();
        #pragma unroll
        for (int i=0;i<4;i++){
            int rr = wave*32 + i*8 + (lane>>3);
            int cg = ((lane&7) ^ (rr&7))*8;
            glds16(qp + (size_t)(bt*128+rr)*512 + h*64 + cg, lQ + (wave*32+i*8)*64);
            glds16(kp + (size_t)(mt*128+rr)*512 + h*64 + cg, lK + (wave*32+i*8)*64);
        }
        __syncthreads();
        f32x4 acc[4][4] = {};
        #pragma unroll
        for (int ks=0;ks<2;++ks){
            bf16x8 af[4], bfv[4];
            #pragma unroll
            for (int i=0;i<4;i++){
                int ra = wr*64 + i*16 + (lane&15);
                af[i] = *(const bf16x8*)&lQ[ra*64 + (((ks*4+(lane>>4)) ^ (ra&7))<<3)];
            }
            #pragma unroll
            for (int i=0;i<4;i++){
                int rb = wc*64 + i*16 + (lane&15);
                bfv[i] = *(const bf16x8*)&lK[rb*64 + (((ks*4+(lane>>4)) ^ (rb&7))<<3)];
            }
            #pragma unroll
            for (int mi=0;mi<4;mi++)
                #pragma unroll
                for (int ni=0;ni<4;ni++)
                    acc[mi][ni] = __builtin_amdgcn_mfma_f32_16x16x32_bf16(af[mi], bfv[ni], acc[mi][ni],0,0,0);
        }
        #pragma unroll
        for (int mi=0;mi<4;mi++)
            #pragma unroll
            for (int ni=0;ni<4;ni++)
                #pragma unroll
                for (int j=0;j<4;j++){
                    int rl = wr*64 + mi*16 + (lane>>4)*4 + j;
                    facc[mi][ni][j] += __expf(0.125f*acc[mi][ni][j]) * lR[h*128 + rl];
                }
    }
    #pragma unroll
    for (int mi=0;mi<4;mi++)
        #pragma unroll
        for (int j=0;j<4;j++){
            size_t r = (size_t)bt*128 + wr*64 + mi*16 + (lane>>4)*4 + j;
            #pragma unroll
            for (int ni=0;ni<4;ni++){
                size_t c = (size_t)mt*128 + wc*64 + ni*16 + (lane&15);
                fo[r*8192 + c] = facc[mi][ni][j];
            }
        }
}

// ---------------- attention pass 3: ctx[b, h*64+a] = sum_m exp(s)*rinv[h,b] * v[m,h,a] ----------------
// grid (btile=32 of 64 rows, h=8), 256 threads. vT is [512][8192] (pre-transposed via swapped GEMM).
__global__ __launch_bounds__(256, 2)
void attn_ctx(const u16* __restrict__ qp, const u16* __restrict__ kp,
              const u16* __restrict__ vTp, const float* __restrict__ rinv,
              u16* __restrict__ ctx)
{
    __shared__ u16 lQ[64*64];
    __shared__ u16 lK[128*64];
    __shared__ u16 lV[64*128];   // vT slice [a][m], 16-chunk swizzle
    __shared__ u16 lP[64*128];   // p [b][m], 16-chunk swizzle
    __shared__ float lRi[64];
    const int tid = threadIdx.x, wave = tid>>6, lane = tid&63;
    const int bt = blockIdx.x, h = blockIdx.y;

    #pragma unroll
    for (int i=0;i<2;i++){
        int rr = wave*16 + i*8 + (lane>>3);
        int cg = ((lane&7) ^ (rr&7))*8;
        glds16(qp + (size_t)(bt*64+rr)*512 + h*64 + cg, lQ + (wave*16+i*8)*64);
    }
    if (tid < 64) lRi[tid] = rinv[h*2048 + bt*64 + tid];

    f32x4 cacc[4] = {};
    for (int mt=0; mt<64; ++mt){
        __syncthreads();
        #pragma unroll
        for (int i=0;i<4;i++){
            int rr = wave*32 + i*8 + (lane>>3);
            int cg = ((lane&7) ^ (rr&7))*8;
            glds16(kp + (size_t)(mt*128+rr)*512 + h*64 + cg, lK + (wave*32+i*8)*64);
        }
        #pragma unroll
        for (int i=0;i<4;i++){
            int rr = wave*16 + i*4 + (lane>>4);
            int cg = ((lane&15) ^ (rr&15))*8;
            glds16(vTp + (size_t)(h*64+rr)*8192 + (size_t)mt*128 + cg, lV + (wave*16+i*4)*128);
        }
        __syncthreads();

        // QK^T: this wave computes s[64b x 32m] at m-cols wave*32..
        f32x4 sacc[4][2] = {};
        #pragma unroll
        for (int ks=0;ks<2;++ks){
            bf16x8 af[4], bk[2];
            #pragma unroll
            for (int i=0;i<4;i++){
                int ra = i*16 + (lane&15);
                af[i] = *(const bf16x8*)&lQ[ra*64 + (((ks*4+(lane>>4)) ^ (ra&7))<<3)];
            }
            #pragma unroll
            for (int i=0;i<2;i++){
                int rb = wave*32 + i*16 + (lane&15);
                bk[i] = *(const bf16x8*)&lK[rb*64 + (((ks*4+(lane>>4)) ^ (rb&7))<<3)];
            }
            #pragma unroll
            for (int mi=0;mi<4;mi++)
                #pragma unroll
                for (int ni=0;ni<2;ni++)
                    sacc[mi][ni] = __builtin_amdgcn_mfma_f32_16x16x32_bf16(af[mi], bk[ni], sacc[mi][ni],0,0,0);
        }
        // p = exp(0.125*s)*rinv -> bf16 -> lP[b][m] (swizzled)
        #pragma unroll
        for (int mi=0;mi<4;mi++)
            #pragma unroll
            for (int j=0;j<4;j++){
                int b = mi*16 + (lane>>4)*4 + j;
                float ri = lRi[b];
                #pragma unroll
                for (int ni=0;ni<2;ni++){
                    int m = wave*32 + ni*16 + (lane&15);
                    float p = __expf(0.125f*sacc[mi][ni][j]) * ri;
                    lP[b*128 + ((((m>>3) ^ (b&15))<<3) | (m&7))] = f2bf(p);
                }
            }
        __syncthreads();
        // PV: this wave computes ctx rows wave*16..+16, all 64 a-cols; K = 128 m (4 k-steps)
        #pragma unroll
        for (int ks=0;ks<4;++ks){
            int ra = wave*16 + (lane&15);
            bf16x8 pa = *(const bf16x8*)&lP[ra*128 + (((ks*4+(lane>>4)) ^ (ra&15))<<3)];
            #pragma unroll
            for (int ai=0;ai<4;ai++){
                int rv = ai*16 + (lane&15);
                bf16x8 vb = *(const bf16x8*)&lV[rv*128 + (((ks*4+(lane>>4)) ^ (rv&15))<<3)];
                cacc[ai] = __builtin_amdgcn_mfma_f32_16x16x32_bf16(pa, vb, cacc[ai],0,0,0);
            }
        }
    }
    #pragma unroll
    for (int ai=0;ai<4;ai++)
        #pragma unroll
        for (int j=0;j<4;j++){
            size_t r = (size_t)bt*64 + wave*16 + (lane>>4)*4 + j;
            size_t c = (size_t)h*64 + ai*16 + (lane&15);
            ctx[r*512 + c] = f2bf(cacc[ai][j]);
        }
}

// ------------------------------------------------------------------
extern "C" void kernel_launch(void* const* d_in, const int* in_sizes, int n_in,
                              void* d_out, int out_size, void* d_ws, size_t ws_size,
                              hipStream_t stream)
{
    const float* x   = (const float*)d_in[0];
    const float* Xc  = (const float*)d_in[1];
    const float* Wq  = (const float*)d_in[2];
    const float* Wk  = (const float*)d_in[3];
    const float* Wv  = (const float*)d_in[4];
    const float* qw  = (const float*)d_in[5];
    const float* kw  = (const float*)d_in[6];
    const float* vw  = (const float*)d_in[7];
    const float* bq  = (const float*)d_in[8];
    const float* bk  = (const float*)d_in[9];
    const float* bv  = (const float*)d_in[10];
    const float* ow  = (const float*)d_in[11];
    const float* ob  = (const float*)d_in[12];
    const float* Wo  = (const float*)d_in[13];
    const float* Wob = (const float*)d_in[14];

    float* out_x    = (float*)d_out;
    float* out_xhat = out_x + (size_t)Bd*Nd;
    float* out_f    = out_xhat + (size_t)Bd*Nd;
    float* out_V    = out_f + (size_t)Bd*Md;

    char* wsb = (char*)d_ws;
    size_t off = 0;
    auto alloc = [&](size_t bytes) -> void* {
        void* p = wsb + off; off += (bytes + 255) & ~(size_t)255; return p;
    };
    u16* xb     = (u16*)alloc((size_t)Bd*Nd*2);
    u16* Xb     = (u16*)alloc((size_t)Md*Nd*2);
    u16* qwb    = (u16*)alloc((size_t)Ed*Ed*2);
    u16* kwb    = (u16*)alloc((size_t)Ed*Ed*2);
    u16* vwb    = (u16*)alloc((size_t)Ed*Nd*2);
    u16* Wqb    = (u16*)alloc((size_t)Nd*Ed*2);
    u16* Wkb    = (u16*)alloc((size_t)Nd*Ed*2);
    u16* Wvb    = (u16*)alloc((size_t)Nd*Nd*2);
    u16* WvTb   = (u16*)alloc((size_t)Nd*Nd*2);
    u16* Wo_b   = (u16*)alloc((size_t)Nd*Ed*2);
    u16* owTb   = (u16*)alloc((size_t)Ed*Ed*2);
    u16* WqqT   = (u16*)alloc((size_t)Ed*Nd*2);
    u16* WkkT   = (u16*)alloc((size_t)Ed*Nd*2);
    u16* WvvT   = (u16*)alloc((size_t)Ed*Nd*2);
    u16* Woo2T  = (u16*)alloc((size_t)Nd*Ed*2);
    float* bo   = (float*)alloc((size_t)Nd*4);
    u16* qb     = (u16*)alloc((size_t)Bd*Ed*2);
    u16* kb     = (u16*)alloc((size_t)Md*Ed*2);
    u16* vTb    = (u16*)alloc((size_t)Ed*Md*2);
    u16* ctxb   = (u16*)alloc((size_t)Bd*Ed*2);
    float* sume = (float*)alloc((size_t)Hd*Bd*4);
    float* rin1 = (float*)alloc((size_t)Hd*Bd*4);
    float* rin8 = (float*)alloc((size_t)Hd*Bd*4);
    if (off > ws_size) return;

    hipMemsetAsync(sume, 0, (size_t)Hd*Bd*4, stream);

    // conversions
    cvt_copy_k<<<Bd*Nd/1024, 256, 0, stream>>>(x, xb, out_x, Bd*Nd);
    cvt_bf16_k<<<Md*Nd/1024, 256, 0, stream>>>(Xc, Xb, Md*Nd);
    cvt_bf16_k<<<Ed*Ed/1024, 256, 0, stream>>>(qw, qwb, Ed*Ed);
    cvt_bf16_k<<<Ed*Ed/1024, 256, 0, stream>>>(kw, kwb, Ed*Ed);
    cvt_bf16_k<<<Ed*Nd/1024, 256, 0, stream>>>(vw, vwb, Ed*Nd);
    cvt_bf16_k<<<Nd*Ed/1024, 256, 0, stream>>>(Wq, Wqb, Nd*Ed);
    cvt_bf16_k<<<Nd*Ed/1024, 256, 0, stream>>>(Wk, Wkb, Nd*Ed);
    cvt_bf16_k<<<Nd*Nd/1024, 256, 0, stream>>>(Wv, Wvb, Nd*Nd);
    cvt_bf16_k<<<Nd*Ed/1024, 256, 0, stream>>>(Wo, Wo_b, Nd*Ed);
    tcvt_k<<<dim3(Nd/32, Nd/32), 256, 0, stream>>>(Wv, WvTb, Nd, Nd);   // W_v_w^T
    tcvt_k<<<dim3(Ed/32, Ed/32), 256, 0, stream>>>(ow, owTb, Ed, Ed);   // out_w^T
    gemv_bo_k<<<Nd/4, 256, 0, stream>>>(Wo, ob, Wob, bo);

    // weight combines (bf16 out)
    gemm_bt<0,0><<<dim3(Nd/128, Ed/128), 256, 0, stream>>>(qwb, Wqb, WqqT, nullptr, Ed, Nd, Ed, 0.125f);
    gemm_bt<0,0><<<dim3(Nd/128, Ed/128), 256, 0, stream>>>(kwb, Wkb, WkkT, nullptr, Ed, Nd, Ed, 1.f);
    gemm_bt<0,0><<<dim3(Nd/128, Ed/128), 256, 0, stream>>>(vwb, Wvb, WvvT, nullptr, Ed, Nd, Nd, 1.f);
    gemm_bt<0,0><<<dim3(Ed/128, Nd/128), 256, 0, stream>>>(Wo_b, owTb, Woo2T, nullptr, Nd, Ed, Ed, 1.f);

    // main projections
    gemm_bt<0,1><<<dim3(Nd/128, Md/128), 256, 0, stream>>>(Xb, WvTb, out_V, nullptr, Md, Nd, Nd, 1.f); // V (f32 out)
    gemm_bt<1,0><<<dim3(Ed/128, Bd/128), 256, 0, stream>>>(xb, WqqT, qb, bq, Bd, Ed, Nd, 1.f);          // q
    gemm_bt<1,0><<<dim3(Ed/128, Md/128), 256, 0, stream>>>(Xb, WkkT, kb, bk, Md, Ed, Nd, 1.f);          // k
    gemm_bt<2,0><<<dim3(Md/128, Ed/128), 256, 0, stream>>>(WvvT, Xb, vTb, bv, Ed, Md, Nd, 1.f);         // vT (row bias)

    // attention
    attn_stats<<<dim3(4, Bd/128, Hd), 256, 0, stream>>>(qb, kb, sume);
    rinv_k<<<Hd*Bd/256, 256, 0, stream>>>(sume, rin1, rin8);
    attn_f<<<dim3(Md/128, Bd/128), 256, 0, stream>>>(qb, kb, rin8, out_f);
    attn_ctx<<<dim3(Bd/64, Hd), 256, 0, stream>>>(qb, kb, vTb, rin1, ctxb);

    // epilogue
    gemm_bt<1,1><<<dim3(Nd/128, Bd/128), 256, 0, stream>>>(ctxb, Woo2T, out_xhat, bo, Bd, Nd, Ed, 1.f);
}

// Round 2
// 328.216 us; speedup vs baseline: 1.1514x; 1.1514x over previous
//
#include <hip/hip_runtime.h>
#include <hip/hip_bf16.h>

typedef unsigned short u16;
typedef __attribute__((ext_vector_type(8))) __bf16 bf16x8;
typedef __attribute__((ext_vector_type(4))) float f32x4;

// dims
#define Bd  2048
#define Nd  768
#define Md  8192
#define Ed  512
#define Hd  8

__device__ __forceinline__ u16 f2bf(float f){
    union { float f; unsigned u; } a; a.f = f;
    unsigned r = a.u + 0x7fffu + ((a.u >> 16) & 1u);
    return (u16)(r >> 16);
}

__device__ __forceinline__ void glds16(const void* g, void* l){
    __builtin_amdgcn_global_load_lds((const __attribute__((address_space(1))) void*)g,
                                     (__attribute__((address_space(3))) void*)l, 16, 0, 0);
}

// ---------------- elementwise conversions ----------------
__global__ void cvt_bf16_k(const float* __restrict__ in, u16* __restrict__ out, int n){
    int i = (blockIdx.x*blockDim.x + threadIdx.x)*4;
    if (i >= n) return;
    float4 v = *(const float4*)(in + i);
    ushort4 u; u.x=f2bf(v.x); u.y=f2bf(v.y); u.z=f2bf(v.z); u.w=f2bf(v.w);
    *(ushort4*)(out + i) = u;
}

__global__ void cvt_copy_k(const float* __restrict__ in, u16* __restrict__ outb,
                           float* __restrict__ outf, int n){
    int i = (blockIdx.x*blockDim.x + threadIdx.x)*4;
    if (i >= n) return;
    float4 v = *(const float4*)(in + i);
    *(float4*)(outf + i) = v;
    ushort4 u; u.x=f2bf(v.x); u.y=f2bf(v.y); u.z=f2bf(v.z); u.w=f2bf(v.w);
    *(ushort4*)(outb + i) = u;
}

// transpose + convert: out[c*R + r] = bf16(in[r*C + c]);  R,C multiples of 32
__global__ void tcvt_k(const float* __restrict__ in, u16* __restrict__ out, int R, int C){
    __shared__ float t[32][33];
    const int tx = threadIdx.x & 31, ty = threadIdx.x >> 5;  // 256 threads
    const int r0 = blockIdx.y*32, c0 = blockIdx.x*32;
    #pragma unroll
    for (int i=0;i<4;i++)
        t[ty + i*8][tx] = in[(size_t)(r0+ty+i*8)*C + c0+tx];
    __syncthreads();
    #pragma unroll
    for (int i=0;i<4;i++)
        out[(size_t)(c0+ty+i*8)*R + r0+tx] = f2bf(t[tx][ty+i*8]);
}

// bo[i] = sum_j W_o_w[i,j]*out_b[j] + W_o_b[i]   (768 rows, K=512)
__global__ void gemv_bo_k(const float* __restrict__ W, const float* __restrict__ ob,
                          const float* __restrict__ wob, float* __restrict__ bo){
    const int wave = threadIdx.x >> 6, lane = threadIdx.x & 63;
    const int i = blockIdx.x*4 + wave;
    float s = 0.f;
    for (int j = lane; j < 512; j += 64) s += W[(size_t)i*512 + j] * ob[j];
    #pragma unroll
    for (int off = 32; off; off >>= 1) s += __shfl_down(s, off);
    if (lane == 0) bo[i] = s + wob[i];
}

__global__ void rinv_k(const float* __restrict__ se, float* __restrict__ r1, float* __restrict__ r8){
    int i = blockIdx.x*256 + threadIdx.x;   // 16384 total
    float v = se[i];
    r1[i] = 1.f / v;
    r8[i] = 0.125f / v;
}

// ---------------- generic GEMM: C[M,N] = alpha*A[M,K]@B[N,K]^T (+bias)  ----------------
template<int BIASMODE, int OUTF32>
__global__ __launch_bounds__(256, 2)
void gemm_bt(const u16* __restrict__ A, const u16* __restrict__ B,
             void* __restrict__ C, const float* __restrict__ bias,
             int M, int N, int K, float alpha)
{
    __shared__ u16 lA[128*64];
    __shared__ u16 lB[128*64];
    const int tid = threadIdx.x;
    const int wave = tid >> 6, lane = tid & 63;
    const int wr = wave >> 1, wc = wave & 1;
    const size_t row0 = (size_t)blockIdx.y * 128;
    const size_t col0 = (size_t)blockIdx.x * 128;

    f32x4 acc[4][4] = {};

    const int srow = wave*32 + (lane>>3);
    const int scol = (lane&7)*8;
    const u16* gA = A + (row0 + srow)*(size_t)K + scol;
    const u16* gB = B + (col0 + srow)*(size_t)K + scol;

    for (int kt = 0; kt < K; kt += 64) {
        #pragma unroll
        for (int i = 0; i < 4; ++i) {
            glds16(gA + (size_t)i*8*K + kt, lA + (wave*32 + i*8)*64);
            glds16(gB + (size_t)i*8*K + kt, lB + (wave*32 + i*8)*64);
        }
        __syncthreads();
        #pragma unroll
        for (int ks = 0; ks < 2; ++ks) {
            bf16x8 af[4], bfv[4];
            #pragma unroll
            for (int i = 0; i < 4; ++i)
                af[i] = *(const bf16x8*)&lA[(wr*64 + i*16 + (lane&15))*64 + ks*32 + (lane>>4)*8];
            #pragma unroll
            for (int i = 0; i < 4; ++i)
                bfv[i] = *(const bf16x8*)&lB[(wc*64 + i*16 + (lane&15))*64 + ks*32 + (lane>>4)*8];
            #pragma unroll
            for (int mi = 0; mi < 4; ++mi)
                #pragma unroll
                for (int ni = 0; ni < 4; ++ni)
                    acc[mi][ni] = __builtin_amdgcn_mfma_f32_16x16x32_bf16(af[mi], bfv[ni], acc[mi][ni], 0, 0, 0);
        }
        __syncthreads();
    }

    #pragma unroll
    for (int mi = 0; mi < 4; ++mi) {
        #pragma unroll
        for (int j = 0; j < 4; ++j) {
            const size_t r = row0 + wr*64 + mi*16 + (lane>>4)*4 + j;
            float badd_r = (BIASMODE==2) ? bias[r] : 0.f;
            #pragma unroll
            for (int ni = 0; ni < 4; ++ni) {
                const size_t c = col0 + wc*64 + ni*16 + (lane&15);
                float v = acc[mi][ni][j] * alpha + ((BIASMODE==1) ? bias[c] : badd_r);
                if (OUTF32) ((float*)C)[r*(size_t)N + c] = v;
                else        ((u16*)C)[r*(size_t)N + c] = f2bf(v);
            }
        }
    }
}

// ---------------- attention pass 1: sumexp[h,b] = sum_m exp(0.125*q_hb . k_hm) ----------------
// 1D grid 512, swizzled so h == blockid % 8 (same-h blocks share K-slice -> same XCD L2).
__global__ __launch_bounds__(256, 2)
void attn_stats(const u16* __restrict__ qp, const u16* __restrict__ kp,
                float* __restrict__ sumexp)
{
    __shared__ u16 lQ[128*64];
    __shared__ u16 lK[128*64];
    const int tid = threadIdx.x, wave = tid>>6, lane = tid&63;
    const int wr = wave>>1, wc = wave&1;
    const int h = blockIdx.x & 7;
    const int rest = blockIdx.x >> 3;     // 0..63
    const int msl = rest & 3, bt = rest >> 2;  // msl 0..3, bt 0..15

    #pragma unroll
    for (int i=0;i<4;i++){
        int rr = wave*32 + i*8 + (lane>>3);
        int cg = ((lane&7) ^ (rr&7))*8;
        glds16(qp + (size_t)(bt*128+rr)*512 + h*64 + cg, lQ + (wave*32+i*8)*64);
    }

    float rsum[4][4] = {};
    for (int mt = msl*16; mt < msl*16+16; ++mt){
        __syncthreads();
        #pragma unroll
        for (int i=0;i<4;i++){
            int rr = wave*32 + i*8 + (lane>>3);
            int cg = ((lane&7) ^ (rr&7))*8;
            glds16(kp + (size_t)(mt*128+rr)*512 + h*64 + cg, lK + (wave*32+i*8)*64);
        }
        __syncthreads();
        f32x4 acc[4][4] = {};
        #pragma unroll
        for (int ks=0;ks<2;++ks){
            bf16x8 af[4], bfv[4];
            #pragma unroll
            for (int i=0;i<4;i++){
                int ra = wr*64 + i*16 + (lane&15);
                af[i] = *(const bf16x8*)&lQ[ra*64 + (((ks*4+(lane>>4)) ^ (ra&7))<<3)];
            }
            #pragma unroll
            for (int i=0;i<4;i++){
                int rb = wc*64 + i*16 + (lane&15);
                bfv[i] = *(const bf16x8*)&lK[rb*64 + (((ks*4+(lane>>4)) ^ (rb&7))<<3)];
            }
            #pragma unroll
            for (int mi=0;mi<4;mi++)
                #pragma unroll
                for (int ni=0;ni<4;ni++)
                    acc[mi][ni] = __builtin_amdgcn_mfma_f32_16x16x32_bf16(af[mi], bfv[ni], acc[mi][ni],0,0,0);
        }
        #pragma unroll
        for (int mi=0;mi<4;mi++)
            #pragma unroll
            for (int ni=0;ni<4;ni++)
                #pragma unroll
                for (int j=0;j<4;j++)
                    rsum[mi][j] += __expf(0.125f*acc[mi][ni][j]);
    }
    #pragma unroll
    for (int mi=0;mi<4;mi++)
        #pragma unroll
        for (int j=0;j<4;j++){
            float s = rsum[mi][j];
            s += __shfl_xor(s, 1); s += __shfl_xor(s, 2);
            s += __shfl_xor(s, 4); s += __shfl_xor(s, 8);
            if ((lane&15)==0){
                int r = bt*128 + wr*64 + mi*16 + (lane>>4)*4 + j;
                atomicAdd(&sumexp[h*2048 + r], s);
            }
        }
}

// ---------------- attention pass 2: f[b,m] = sum_h exp(s_hbm)*rinv8[h,b] ----------------
__global__ __launch_bounds__(256, 2)
void attn_f(const u16* __restrict__ qp, const u16* __restrict__ kp,
            const float* __restrict__ rinv8, float* __restrict__ fo)
{
    __shared__ u16 lQ[128*64];
    __shared__ u16 lK[128*64];
    __shared__ float lR[8*128];
    const int tid = threadIdx.x, wave = tid>>6, lane = tid&63;
    const int wr = wave>>1, wc = wave&1;
    const int mt = blockIdx.x, bt = blockIdx.y;

    #pragma unroll
    for (int i=0;i<4;i++){
        int id = i*256 + tid;
        lR[id] = rinv8[(id>>7)*2048 + bt*128 + (id&127)];
    }

    float facc[4][4][4] = {};
    for (int h=0; h<8; ++h){
        __syncthreads();
        #pragma unroll
        for (int i=0;i<4;i++){
            int rr = wave*32 + i*8 + (lane>>3);
            int cg = ((lane&7) ^ (rr&7))*8;
            glds16(qp + (size_t)(bt*128+rr)*512 + h*64 + cg, lQ + (wave*32+i*8)*64);
            glds16(kp + (size_t)(mt*128+rr)*512 + h*64 + cg, lK + (wave*32+i*8)*64);
        }
        __syncthreads();
        f32x4 acc[4][4] = {};
        #pragma unroll
        for (int ks=0;ks<2;++ks){
            bf16x8 af[4], bfv[4];
            #pragma unroll
            for (int i=0;i<4;i++){
                int ra = wr*64 + i*16 + (lane&15);
                af[i] = *(const bf16x8*)&lQ[ra*64 + (((ks*4+(lane>>4)) ^ (ra&7))<<3)];
            }
            #pragma unroll
            for (int i=0;i<4;i++){
                int rb = wc*64 + i*16 + (lane&15);
                bfv[i] = *(const bf16x8*)&lK[rb*64 + (((ks*4+(lane>>4)) ^ (rb&7))<<3)];
            }
            #pragma unroll
            for (int mi=0;mi<4;mi++)
                #pragma unroll
                for (int ni=0;ni<4;ni++)
                    acc[mi][ni] = __builtin_amdgcn_mfma_f32_16x16x32_bf16(af[mi], bfv[ni], acc[mi][ni],0,0,0);
        }
        #pragma unroll
        for (int mi=0;mi<4;mi++)
            #pragma unroll
            for (int ni=0;ni<4;ni++)
                #pragma unroll
                for (int j=0;j<4;j++){
                    int rl = wr*64 + mi*16 + (lane>>4)*4 + j;
                    facc[mi][ni][j] += __expf(0.125f*acc[mi][ni][j]) * lR[h*128 + rl];
                }
    }
    #pragma unroll
    for (int mi=0;mi<4;mi++)
        #pragma unroll
        for (int j=0;j<4;j++){
            size_t r = (size_t)bt*128 + wr*64 + mi*16 + (lane>>4)*4 + j;
            #pragma unroll
            for (int ni=0;ni<4;ni++){
                size_t c = (size_t)mt*128 + wc*64 + ni*16 + (lane&15);
                fo[r*8192 + c] = facc[mi][ni][j];
            }
        }
}

// ---------------- attention pass 3 (m-split partials) ----------------
// 1D grid 1024: h = id&7 (XCD-chunk by head), rest: msl = rest&3, bt = rest>>2 (0..31).
// part[msl][b][h*64+a] f32; each block covers 64 b-rows x 64 a-cols, m in [msl*2048, +2048).
__global__ __launch_bounds__(256, 2)
void attn_ctx_part(const u16* __restrict__ qp, const u16* __restrict__ kp,
                   const u16* __restrict__ vTp, const float* __restrict__ rinv,
                   float* __restrict__ part)
{
    __shared__ u16 lQ[64*64];
    __shared__ u16 lK[128*64];
    __shared__ u16 lV[64*128];
    __shared__ u16 lP[64*128];
    __shared__ float lRi[64];
    const int tid = threadIdx.x, wave = tid>>6, lane = tid&63;
    const int h = blockIdx.x & 7;
    const int rest = blockIdx.x >> 3;   // 0..127
    const int msl = rest & 3, bt = rest >> 2;  // msl 0..3, bt 0..31

    #pragma unroll
    for (int i=0;i<2;i++){
        int rr = wave*16 + i*8 + (lane>>3);
        int cg = ((lane&7) ^ (rr&7))*8;
        glds16(qp + (size_t)(bt*64+rr)*512 + h*64 + cg, lQ + (wave*16+i*8)*64);
    }
    if (tid < 64) lRi[tid] = rinv[h*2048 + bt*64 + tid];

    f32x4 cacc[4] = {};
    for (int mt = msl*16; mt < msl*16+16; ++mt){
        __syncthreads();
        #pragma unroll
        for (int i=0;i<4;i++){
            int rr = wave*32 + i*8 + (lane>>3);
            int cg = ((lane&7) ^ (rr&7))*8;
            glds16(kp + (size_t)(mt*128+rr)*512 + h*64 + cg, lK + (wave*32+i*8)*64);
        }
        #pragma unroll
        for (int i=0;i<4;i++){
            int rr = wave*16 + i*4 + (lane>>4);
            int cg = ((lane&15) ^ (rr&15))*8;
            glds16(vTp + (size_t)(h*64+rr)*8192 + (size_t)mt*128 + cg, lV + (wave*16+i*4)*128);
        }
        __syncthreads();

        // QK^T: this wave computes s[64b x 32m] at m-cols wave*32..
        f32x4 sacc[4][2] = {};
        #pragma unroll
        for (int ks=0;ks<2;++ks){
            bf16x8 af[4], bk[2];
            #pragma unroll
            for (int i=0;i<4;i++){
                int ra = i*16 + (lane&15);
                af[i] = *(const bf16x8*)&lQ[ra*64 + (((ks*4+(lane>>4)) ^ (ra&7))<<3)];
            }
            #pragma unroll
            for (int i=0;i<2;i++){
                int rb = wave*32 + i*16 + (lane&15);
                bk[i] = *(const bf16x8*)&lK[rb*64 + (((ks*4+(lane>>4)) ^ (rb&7))<<3)];
            }
            #pragma unroll
            for (int mi=0;mi<4;mi++)
                #pragma unroll
                for (int ni=0;ni<2;ni++)
                    sacc[mi][ni] = __builtin_amdgcn_mfma_f32_16x16x32_bf16(af[mi], bk[ni], sacc[mi][ni],0,0,0);
        }
        // p = exp(0.125*s)*rinv -> bf16 -> lP[b][m] (swizzled)
        #pragma unroll
        for (int mi=0;mi<4;mi++)
            #pragma unroll
            for (int j=0;j<4;j++){
                int b = mi*16 + (lane>>4)*4 + j;
                float ri = lRi[b];
                #pragma unroll
                for (int ni=0;ni<2;ni++){
                    int m = wave*32 + ni*16 + (lane&15);
                    float p = __expf(0.125f*sacc[mi][ni][j]) * ri;
                    lP[b*128 + ((((m>>3) ^ (b&15))<<3) | (m&7))] = f2bf(p);
                }
            }
        __syncthreads();
        // PV: this wave computes ctx rows wave*16..+16, all 64 a-cols
        #pragma unroll
        for (int ks=0;ks<4;++ks){
            int ra = wave*16 + (lane&15);
            bf16x8 pa = *(const bf16x8*)&lP[ra*128 + (((ks*4+(lane>>4)) ^ (ra&15))<<3)];
            #pragma unroll
            for (int ai=0;ai<4;ai++){
                int rv = ai*16 + (lane&15);
                bf16x8 vb = *(const bf16x8*)&lV[rv*128 + (((ks*4+(lane>>4)) ^ (rv&15))<<3)];
                cacc[ai] = __builtin_amdgcn_mfma_f32_16x16x32_bf16(pa, vb, cacc[ai],0,0,0);
            }
        }
    }
    #pragma unroll
    for (int ai=0;ai<4;ai++)
        #pragma unroll
        for (int j=0;j<4;j++){
            size_t r = (size_t)bt*64 + wave*16 + (lane>>4)*4 + j;
            size_t c = (size_t)h*64 + ai*16 + (lane&15);
            part[((size_t)msl<<20) + r*512 + c] = cacc[ai][j];
        }
}

__global__ void ctx_reduce_k(const float* __restrict__ part, u16* __restrict__ ctx){
    int i = (blockIdx.x*256 + threadIdx.x)*4;   // over 2048*512
    float4 a = *(const float4*)(part + i);
    float4 b = *(const float4*)(part + (1u<<20) + i);
    float4 c = *(const float4*)(part + (2u<<20) + i);
    float4 d = *(const float4*)(part + (3u<<20) + i);
    ushort4 u;
    u.x = f2bf(a.x+b.x+c.x+d.x);
    u.y = f2bf(a.y+b.y+c.y+d.y);
    u.z = f2bf(a.z+b.z+c.z+d.z);
    u.w = f2bf(a.w+b.w+c.w+d.w);
    *(ushort4*)(ctx + i) = u;
}

// ------------------------------------------------------------------
extern "C" void kernel_launch(void* const* d_in, const int* in_sizes, int n_in,
                              void* d_out, int out_size, void* d_ws, size_t ws_size,
                              hipStream_t stream)
{
    const float* x   = (const float*)d_in[0];
    const float* Xc  = (const float*)d_in[1];
    const float* Wq  = (const float*)d_in[2];
    const float* Wk  = (const float*)d_in[3];
    const float* Wv  = (const float*)d_in[4];
    const float* qw  = (const float*)d_in[5];
    const float* kw  = (const float*)d_in[6];
    const float* vw  = (const float*)d_in[7];
    const float* bq  = (const float*)d_in[8];
    const float* bk  = (const float*)d_in[9];
    const float* bv  = (const float*)d_in[10];
    const float* ow  = (const float*)d_in[11];
    const float* ob  = (const float*)d_in[12];
    const float* Wo  = (const float*)d_in[13];
    const float* Wob = (const float*)d_in[14];

    float* out_x    = (float*)d_out;
    float* out_xhat = out_x + (size_t)Bd*Nd;
    float* out_f    = out_xhat + (size_t)Bd*Nd;
    float* out_V    = out_f + (size_t)Bd*Md;

    char* wsb = (char*)d_ws;
    size_t off = 0;
    auto alloc = [&](size_t bytes) -> void* {
        void* p = wsb + off; off += (bytes + 255) & ~(size_t)255; return p;
    };
    u16* xb     = (u16*)alloc((size_t)Bd*Nd*2);
    u16* Xb     = (u16*)alloc((size_t)Md*Nd*2);
    u16* qwb    = (u16*)alloc((size_t)Ed*Ed*2);
    u16* kwb    = (u16*)alloc((size_t)Ed*Ed*2);
    u16* vwb    = (u16*)alloc((size_t)Ed*Nd*2);
    u16* Wqb    = (u16*)alloc((size_t)Nd*Ed*2);
    u16* Wkb    = (u16*)alloc((size_t)Nd*Ed*2);
    u16* Wvb    = (u16*)alloc((size_t)Nd*Nd*2);
    u16* WvTb   = (u16*)alloc((size_t)Nd*Nd*2);
    u16* Wo_b   = (u16*)alloc((size_t)Nd*Ed*2);
    u16* owTb   = (u16*)alloc((size_t)Ed*Ed*2);
    u16* WqqT   = (u16*)alloc((size_t)Ed*Nd*2);
    u16* WkkT   = (u16*)alloc((size_t)Ed*Nd*2);
    u16* WvvT   = (u16*)alloc((size_t)Ed*Nd*2);
    u16* Woo2T  = (u16*)alloc((size_t)Nd*Ed*2);
    float* bo   = (float*)alloc((size_t)Nd*4);
    u16* qb     = (u16*)alloc((size_t)Bd*Ed*2);
    u16* kb     = (u16*)alloc((size_t)Md*Ed*2);
    u16* vTb    = (u16*)alloc((size_t)Ed*Md*2);
    u16* ctxb   = (u16*)alloc((size_t)Bd*Ed*2);
    float* sume = (float*)alloc((size_t)Hd*Bd*4);
    float* rin1 = (float*)alloc((size_t)Hd*Bd*4);
    float* rin8 = (float*)alloc((size_t)Hd*Bd*4);
    float* part = (float*)alloc((size_t)4*Bd*Ed*4);   // 16 MB ctx partials
    if (off > ws_size) return;

    hipMemsetAsync(sume, 0, (size_t)Hd*Bd*4, stream);

    // conversions
    cvt_copy_k<<<Bd*Nd/1024, 256, 0, stream>>>(x, xb, out_x, Bd*Nd);
    cvt_bf16_k<<<Md*Nd/1024, 256, 0, stream>>>(Xc, Xb, Md*Nd);
    cvt_bf16_k<<<Ed*Ed/1024, 256, 0, stream>>>(qw, qwb, Ed*Ed);
    cvt_bf16_k<<<Ed*Ed/1024, 256, 0, stream>>>(kw, kwb, Ed*Ed);
    cvt_bf16_k<<<Ed*Nd/1024, 256, 0, stream>>>(vw, vwb, Ed*Nd);
    cvt_bf16_k<<<Nd*Ed/1024, 256, 0, stream>>>(Wq, Wqb, Nd*Ed);
    cvt_bf16_k<<<Nd*Ed/1024, 256, 0, stream>>>(Wk, Wkb, Nd*Ed);
    cvt_bf16_k<<<Nd*Nd/1024, 256, 0, stream>>>(Wv, Wvb, Nd*Nd);
    cvt_bf16_k<<<Nd*Ed/1024, 256, 0, stream>>>(Wo, Wo_b, Nd*Ed);
    tcvt_k<<<dim3(Nd/32, Nd/32), 256, 0, stream>>>(Wv, WvTb, Nd, Nd);   // W_v_w^T
    tcvt_k<<<dim3(Ed/32, Ed/32), 256, 0, stream>>>(ow, owTb, Ed, Ed);   // out_w^T
    gemv_bo_k<<<Nd/4, 256, 0, stream>>>(Wo, ob, Wob, bo);

    // weight combines (bf16 out)
    gemm_bt<0,0><<<dim3(Nd/128, Ed/128), 256, 0, stream>>>(qwb, Wqb, WqqT, nullptr, Ed, Nd, Ed, 0.125f);
    gemm_bt<0,0><<<dim3(Nd/128, Ed/128), 256, 0, stream>>>(kwb, Wkb, WkkT, nullptr, Ed, Nd, Ed, 1.f);
    gemm_bt<0,0><<<dim3(Nd/128, Ed/128), 256, 0, stream>>>(vwb, Wvb, WvvT, nullptr, Ed, Nd, Nd, 1.f);
    gemm_bt<0,0><<<dim3(Ed/128, Nd/128), 256, 0, stream>>>(Wo_b, owTb, Woo2T, nullptr, Nd, Ed, Ed, 1.f);

    // main projections
    gemm_bt<0,1><<<dim3(Nd/128, Md/128), 256, 0, stream>>>(Xb, WvTb, out_V, nullptr, Md, Nd, Nd, 1.f); // V (f32 out)
    gemm_bt<1,0><<<dim3(Ed/128, Bd/128), 256, 0, stream>>>(xb, WqqT, qb, bq, Bd, Ed, Nd, 1.f);          // q
    gemm_bt<1,0><<<dim3(Ed/128, Md/128), 256, 0, stream>>>(Xb, WkkT, kb, bk, Md, Ed, Nd, 1.f);          // k
    gemm_bt<2,0><<<dim3(Md/128, Ed/128), 256, 0, stream>>>(WvvT, Xb, vTb, bv, Ed, Md, Nd, 1.f);         // vT (row bias)

    // attention
    attn_stats<<<512, 256, 0, stream>>>(qb, kb, sume);
    rinv_k<<<Hd*Bd/256, 256, 0, stream>>>(sume, rin1, rin8);
    attn_f<<<dim3(Md/128, Bd/128), 256, 0, stream>>>(qb, kb, rin8, out_f);
    attn_ctx_part<<<1024, 256, 0, stream>>>(qb, kb, vTb, rin1, part);
    ctx_reduce_k<<<Bd*Ed/1024, 256, 0, stream>>>(part, ctxb);

    // epilogue
    gemm_bt<1,1><<<dim3(Nd/128, Bd/128), 256, 0, stream>>>(ctxb, Woo2T, out_xhat, bo, Bd, Nd, Ed, 1.f);
}

// Round 3
// 287.705 us; speedup vs baseline: 1.3135x; 1.1408x over previous
//
#include <hip/hip_runtime.h>
#include <hip/hip_bf16.h>

typedef unsigned short u16;
typedef __attribute__((ext_vector_type(8))) __bf16 bf16x8;
typedef __attribute__((ext_vector_type(4))) float f32x4;

// dims
#define Bd  2048
#define Nd  768
#define Md  8192
#define Ed  512
#define Hd  8
#define NSL 4          // m-slices for ctx partials
#define AIT 32         // iters per attn_sc block = (Md/NSL)/64

__device__ __forceinline__ u16 f2bf(float f){
    union { float f; unsigned u; } a; a.f = f;
    unsigned r = a.u + 0x7fffu + ((a.u >> 16) & 1u);
    return (u16)(r >> 16);
}

__device__ __forceinline__ void glds16(const void* g, void* l){
    __builtin_amdgcn_global_load_lds((const __attribute__((address_space(1))) void*)g,
                                     (__attribute__((address_space(3))) void*)l, 16, 0, 0);
}

// ---------------- elementwise conversions ----------------
__global__ void cvt_bf16_k(const float* __restrict__ in, u16* __restrict__ out, int n){
    int i = (blockIdx.x*blockDim.x + threadIdx.x)*4;
    if (i >= n) return;
    float4 v = *(const float4*)(in + i);
    ushort4 u; u.x=f2bf(v.x); u.y=f2bf(v.y); u.z=f2bf(v.z); u.w=f2bf(v.w);
    *(ushort4*)(out + i) = u;
}

__global__ void cvt_copy_k(const float* __restrict__ in, u16* __restrict__ outb,
                           float* __restrict__ outf, int n){
    int i = (blockIdx.x*blockDim.x + threadIdx.x)*4;
    if (i >= n) return;
    float4 v = *(const float4*)(in + i);
    *(float4*)(outf + i) = v;
    ushort4 u; u.x=f2bf(v.x); u.y=f2bf(v.y); u.z=f2bf(v.z); u.w=f2bf(v.w);
    *(ushort4*)(outb + i) = u;
}

// transpose + convert: out[c*R + r] = bf16(in[r*C + c]);  R,C multiples of 32
__global__ void tcvt_k(const float* __restrict__ in, u16* __restrict__ out, int R, int C){
    __shared__ float t[32][33];
    const int tx = threadIdx.x & 31, ty = threadIdx.x >> 5;  // 256 threads
    const int r0 = blockIdx.y*32, c0 = blockIdx.x*32;
    #pragma unroll
    for (int i=0;i<4;i++)
        t[ty + i*8][tx] = in[(size_t)(r0+ty+i*8)*C + c0+tx];
    __syncthreads();
    #pragma unroll
    for (int i=0;i<4;i++)
        out[(size_t)(c0+ty+i*8)*R + r0+tx] = f2bf(t[tx][ty+i*8]);
}

// bo[i] = sum_j W_o_w[i,j]*out_b[j] + W_o_b[i]   (768 rows, K=512)
__global__ void gemv_bo_k(const float* __restrict__ W, const float* __restrict__ ob,
                          const float* __restrict__ wob, float* __restrict__ bo){
    const int wave = threadIdx.x >> 6, lane = threadIdx.x & 63;
    const int i = blockIdx.x*4 + wave;
    float s = 0.f;
    for (int j = lane; j < 512; j += 64) s += W[(size_t)i*512 + j] * ob[j];
    #pragma unroll
    for (int off = 32; off; off >>= 1) s += __shfl_down(s, off);
    if (lane == 0) bo[i] = s + wob[i];
}

__global__ void rinv_k(const float* __restrict__ se, float* __restrict__ r1, float* __restrict__ r8){
    int i = blockIdx.x*256 + threadIdx.x;   // 16384 total
    float v = se[i];
    r1[i] = 1.f / v;
    r8[i] = 0.125f / v;
}

// ---------------- generic GEMM: C[M,N] = alpha*A[M,K]@B[N,K]^T (+bias)  ----------------
template<int BIASMODE, int OUTF32>
__global__ __launch_bounds__(256, 2)
void gemm_bt(const u16* __restrict__ A, const u16* __restrict__ B,
             void* __restrict__ C, const float* __restrict__ bias,
             int M, int N, int K, float alpha)
{
    __shared__ u16 lA[128*64];
    __shared__ u16 lB[128*64];
    const int tid = threadIdx.x;
    const int wave = tid >> 6, lane = tid & 63;
    const int wr = wave >> 1, wc = wave & 1;
    const size_t row0 = (size_t)blockIdx.y * 128;
    const size_t col0 = (size_t)blockIdx.x * 128;

    f32x4 acc[4][4] = {};

    const int srow = wave*32 + (lane>>3);
    const int scol = (lane&7)*8;
    const u16* gA = A + (row0 + srow)*(size_t)K + scol;
    const u16* gB = B + (col0 + srow)*(size_t)K + scol;

    for (int kt = 0; kt < K; kt += 64) {
        #pragma unroll
        for (int i = 0; i < 4; ++i) {
            glds16(gA + (size_t)i*8*K + kt, lA + (wave*32 + i*8)*64);
            glds16(gB + (size_t)i*8*K + kt, lB + (wave*32 + i*8)*64);
        }
        __syncthreads();
        #pragma unroll
        for (int ks = 0; ks < 2; ++ks) {
            bf16x8 af[4], bfv[4];
            #pragma unroll
            for (int i = 0; i < 4; ++i)
                af[i] = *(const bf16x8*)&lA[(wr*64 + i*16 + (lane&15))*64 + ks*32 + (lane>>4)*8];
            #pragma unroll
            for (int i = 0; i < 4; ++i)
                bfv[i] = *(const bf16x8*)&lB[(wc*64 + i*16 + (lane&15))*64 + ks*32 + (lane>>4)*8];
            #pragma unroll
            for (int mi = 0; mi < 4; ++mi)
                #pragma unroll
                for (int ni = 0; ni < 4; ++ni)
                    acc[mi][ni] = __builtin_amdgcn_mfma_f32_16x16x32_bf16(af[mi], bfv[ni], acc[mi][ni], 0, 0, 0);
        }
        __syncthreads();
    }

    #pragma unroll
    for (int mi = 0; mi < 4; ++mi) {
        #pragma unroll
        for (int j = 0; j < 4; ++j) {
            const size_t r = row0 + wr*64 + mi*16 + (lane>>4)*4 + j;
            float badd_r = (BIASMODE==2) ? bias[r] : 0.f;
            #pragma unroll
            for (int ni = 0; ni < 4; ++ni) {
                const size_t c = col0 + wc*64 + ni*16 + (lane&15);
                float v = acc[mi][ni][j] * alpha + ((BIASMODE==1) ? bias[c] : badd_r);
                if (OUTF32) ((float*)C)[r*(size_t)N + c] = v;
                else        ((u16*)C)[r*(size_t)N + c] = f2bf(v);
            }
        }
    }
}

// ---------------- fused attention: sumexp + unnormalized ctx partials ----------------
// grid 512: h = id&7 (XCD-chunk), rest: msl = rest&3, bt = rest>>2 (0..15).
// Per block: b-tile 128 (Q in regs, wave owns 32 rows), m-range 2048 in 32 iters of 64.
// part[msl][b][h*64+a] += exp(0.125 q.k) * v  (f32, unnormalized);
// sumexp[h][b] atomically accumulated.
__global__ __launch_bounds__(256, 2)
void attn_sc(const u16* __restrict__ qp, const u16* __restrict__ kp,
             const u16* __restrict__ vTp, float* __restrict__ sumexp,
             float* __restrict__ part)
{
    __shared__ u16 lK[2][64*64];
    __shared__ u16 lV[2][64*64];
    __shared__ u16 lP[4][32*64];
    const int tid = threadIdx.x, w = tid>>6, l = tid&63;
    const int h = blockIdx.x & 7;
    const int rest = blockIdx.x >> 3;
    const int msl = rest & (NSL-1), bt = rest >> 2;   // msl 0..3, bt 0..15
    const int m0 = msl * (AIT*64);

    // Q fragments in registers: wave owns rows bt*128 + w*32 .. +32
    bf16x8 qf[2][2];
    #pragma unroll
    for (int rt=0; rt<2; ++rt)
        #pragma unroll
        for (int ks=0; ks<2; ++ks)
            qf[rt][ks] = *(const bf16x8*)&qp[(size_t)(bt*128 + w*32 + rt*16 + (l&15))*512
                                            + h*64 + ks*32 + (l>>4)*8];

    const int sr = w*8 + (l>>3);            // staging row within 32-row group
    const int srcc = ((l&7) ^ (l>>3))*8;    // pre-swizzled source column
    u16* lPw = lP[w];

    auto STAGE = [&](int buf, int mb){
        #pragma unroll
        for (int i=0;i<2;i++)
            glds16(kp + (size_t)(mb + i*32 + sr)*512 + h*64 + srcc, &lK[buf][(i*32 + w*8)*64]);
        #pragma unroll
        for (int i=0;i<2;i++)
            glds16(vTp + (size_t)(h*64 + i*32 + sr)*8192 + mb + srcc, &lV[buf][(i*32 + w*8)*64]);
    };

    STAGE(0, m0);
    __syncthreads();

    f32x4 cacc[2][4] = {};
    float rs[2][4] = {};
    int cur = 0;
    for (int t=0; t<AIT; ++t){
        if (t+1 < AIT) STAGE(cur^1, m0 + (t+1)*64);

        // QK^T: s[32b x 64m] per wave
        f32x4 sacc[2][4] = {};
        #pragma unroll
        for (int ks=0; ks<2; ++ks){
            bf16x8 bk[4];
            #pragma unroll
            for (int ct=0; ct<4; ++ct){
                int rb = ct*16 + (l&15);
                bk[ct] = *(const bf16x8*)&lK[cur][rb*64 + (((ks*4+(l>>4)) ^ (rb&7))<<3)];
            }
            #pragma unroll
            for (int rt=0; rt<2; ++rt)
                #pragma unroll
                for (int ct=0; ct<4; ++ct)
                    sacc[rt][ct] = __builtin_amdgcn_mfma_f32_16x16x32_bf16(qf[rt][ks], bk[ct], sacc[rt][ct],0,0,0);
        }
        // p = exp(0.125 s) (unnormalized) -> private lP; rs accumulation
        #pragma unroll
        for (int rt=0; rt<2; ++rt)
            #pragma unroll
            for (int ct=0; ct<4; ++ct)
                #pragma unroll
                for (int j=0; j<4; ++j){
                    int row = rt*16 + (l>>4)*4 + j;       // 0..31
                    int m   = ct*16 + (l&15);             // 0..63
                    float p = __expf(0.125f*sacc[rt][ct][j]);
                    rs[rt][j] += p;
                    int sw = (row&7) ^ ((row>>3)&1);
                    lPw[row*64 + (((m>>3) ^ sw)<<3) + (m&7)] = f2bf(p);
                }
        // PV: ctx[32b x 64a] += P[32b x 64m] @ V[64m x 64a]
        #pragma unroll
        for (int ks2=0; ks2<2; ++ks2){
            #pragma unroll
            for (int rt=0; rt<2; ++rt){
                int rowa = rt*16 + (l&15);
                int swa = (rowa&7) ^ ((rowa>>3)&1);
                bf16x8 pa = *(const bf16x8*)&lPw[rowa*64 + (((ks2*4+(l>>4)) ^ swa)<<3)];
                #pragma unroll
                for (int ai=0; ai<4; ++ai){
                    int rv = ai*16 + (l&15);
                    bf16x8 vb = *(const bf16x8*)&lV[cur][rv*64 + (((ks2*4+(l>>4)) ^ (rv&7))<<3)];
                    cacc[rt][ai] = __builtin_amdgcn_mfma_f32_16x16x32_bf16(pa, vb, cacc[rt][ai],0,0,0);
                }
            }
        }
        __syncthreads();
        cur ^= 1;
    }

    // write ctx partials (f32, unnormalized)
    #pragma unroll
    for (int rt=0; rt<2; ++rt)
        #pragma unroll
        for (int ai=0; ai<4; ++ai)
            #pragma unroll
            for (int j=0; j<4; ++j){
                size_t r = (size_t)bt*128 + w*32 + rt*16 + (l>>4)*4 + j;
                size_t c = (size_t)h*64 + ai*16 + (l&15);
                part[((size_t)msl<<20) + r*512 + c] = cacc[rt][ai][j];
            }
    // sumexp atomics (one per row)
    #pragma unroll
    for (int rt=0; rt<2; ++rt)
        #pragma unroll
        for (int j=0; j<4; ++j){
            float s = rs[rt][j];
            s += __shfl_xor(s, 1); s += __shfl_xor(s, 2);
            s += __shfl_xor(s, 4); s += __shfl_xor(s, 8);
            if ((l&15)==0)
                atomicAdd(&sumexp[h*2048 + bt*128 + w*32 + rt*16 + (l>>4)*4 + j], s);
        }
}

// ---------------- attention pass 2: f[b,m] = sum_h exp(s_hbm)*rinv8[h,b] ----------------
// dbuf-prefetched across the h-loop.
__global__ __launch_bounds__(256, 2)
void attn_f(const u16* __restrict__ qp, const u16* __restrict__ kp,
            const float* __restrict__ rinv8, float* __restrict__ fo)
{
    __shared__ u16 lQ[2][128*64];
    __shared__ u16 lK[2][128*64];
    __shared__ float lR[8*128];
    const int tid = threadIdx.x, w = tid>>6, l = tid&63;
    const int wr = w>>1, wc = w&1;
    const int mt = blockIdx.x, bt = blockIdx.y;

    const int sr = w*8 + (l>>3);
    const int srcc = ((l&7) ^ (l>>3))*8;

    auto STAGE = [&](int buf, int h){
        #pragma unroll
        for (int i=0;i<4;i++){
            glds16(qp + (size_t)(bt*128 + i*32 + sr)*512 + h*64 + srcc, &lQ[buf][(i*32 + w*8)*64]);
            glds16(kp + (size_t)(mt*128 + i*32 + sr)*512 + h*64 + srcc, &lK[buf][(i*32 + w*8)*64]);
        }
    };

    #pragma unroll
    for (int i=0;i<4;i++){
        int id = i*256 + tid;
        lR[id] = rinv8[(id>>7)*2048 + bt*128 + (id&127)];
    }
    STAGE(0, 0);
    __syncthreads();

    float facc[4][4][4] = {};
    int cur = 0;
    for (int h=0; h<8; ++h){
        if (h < 7) STAGE(cur^1, h+1);
        f32x4 acc[4][4] = {};
        #pragma unroll
        for (int ks=0; ks<2; ++ks){
            bf16x8 af[4], bfv[4];
            #pragma unroll
            for (int i=0;i<4;i++){
                int ra = wr*64 + i*16 + (l&15);
                af[i] = *(const bf16x8*)&lQ[cur][ra*64 + (((ks*4+(l>>4)) ^ (ra&7))<<3)];
            }
            #pragma unroll
            for (int i=0;i<4;i++){
                int rb = wc*64 + i*16 + (l&15);
                bfv[i] = *(const bf16x8*)&lK[cur][rb*64 + (((ks*4+(l>>4)) ^ (rb&7))<<3)];
            }
            #pragma unroll
            for (int mi=0;mi<4;mi++)
                #pragma unroll
                for (int ni=0;ni<4;ni++)
                    acc[mi][ni] = __builtin_amdgcn_mfma_f32_16x16x32_bf16(af[mi], bfv[ni], acc[mi][ni],0,0,0);
        }
        #pragma unroll
        for (int mi=0;mi<4;mi++)
            #pragma unroll
            for (int ni=0;ni<4;ni++)
                #pragma unroll
                for (int j=0;j<4;j++){
                    int rl = wr*64 + mi*16 + (l>>4)*4 + j;
                    facc[mi][ni][j] += __expf(0.125f*acc[mi][ni][j]) * lR[h*128 + rl];
                }
        __syncthreads();
        cur ^= 1;
    }
    #pragma unroll
    for (int mi=0;mi<4;mi++)
        #pragma unroll
        for (int j=0;j<4;j++){
            size_t r = (size_t)bt*128 + wr*64 + mi*16 + (l>>4)*4 + j;
            #pragma unroll
            for (int ni=0;ni<4;ni++){
                size_t c = (size_t)mt*128 + wc*64 + ni*16 + (l&15);
                fo[r*8192 + c] = facc[mi][ni][j];
            }
        }
}

// ctx[b,e] = sum_msl part[msl][b][e] * rinv1[h(e), b]
__global__ void ctx_reduce_k(const float* __restrict__ part, const float* __restrict__ rin1,
                             u16* __restrict__ ctx){
    int i = (blockIdx.x*256 + threadIdx.x)*4;   // over 2048*512
    int b = i >> 9, h = (i >> 6) & 7;
    float ri = rin1[h*2048 + b];
    float4 a = *(const float4*)(part + i);
    float4 bb = *(const float4*)(part + (1u<<20) + i);
    float4 c = *(const float4*)(part + (2u<<20) + i);
    float4 d = *(const float4*)(part + (3u<<20) + i);
    ushort4 u;
    u.x = f2bf((a.x+bb.x+c.x+d.x)*ri);
    u.y = f2bf((a.y+bb.y+c.y+d.y)*ri);
    u.z = f2bf((a.z+bb.z+c.z+d.z)*ri);
    u.w = f2bf((a.w+bb.w+c.w+d.w)*ri);
    *(ushort4*)(ctx + i) = u;
}

// ------------------------------------------------------------------
extern "C" void kernel_launch(void* const* d_in, const int* in_sizes, int n_in,
                              void* d_out, int out_size, void* d_ws, size_t ws_size,
                              hipStream_t stream)
{
    const float* x   = (const float*)d_in[0];
    const float* Xc  = (const float*)d_in[1];
    const float* Wq  = (const float*)d_in[2];
    const float* Wk  = (const float*)d_in[3];
    const float* Wv  = (const float*)d_in[4];
    const float* qw  = (const float*)d_in[5];
    const float* kw  = (const float*)d_in[6];
    const float* vw  = (const float*)d_in[7];
    const float* bq  = (const float*)d_in[8];
    const float* bk  = (const float*)d_in[9];
    const float* bv  = (const float*)d_in[10];
    const float* ow  = (const float*)d_in[11];
    const float* ob  = (const float*)d_in[12];
    const float* Wo  = (const float*)d_in[13];
    const float* Wob = (const float*)d_in[14];

    float* out_x    = (float*)d_out;
    float* out_xhat = out_x + (size_t)Bd*Nd;
    float* out_f    = out_xhat + (size_t)Bd*Nd;
    float* out_V    = out_f + (size_t)Bd*Md;

    char* wsb = (char*)d_ws;
    size_t off = 0;
    auto alloc = [&](size_t bytes) -> void* {
        void* p = wsb + off; off += (bytes + 255) & ~(size_t)255; return p;
    };
    u16* xb     = (u16*)alloc((size_t)Bd*Nd*2);
    u16* Xb     = (u16*)alloc((size_t)Md*Nd*2);
    u16* qwb    = (u16*)alloc((size_t)Ed*Ed*2);
    u16* kwb    = (u16*)alloc((size_t)Ed*Ed*2);
    u16* vwb    = (u16*)alloc((size_t)Ed*Nd*2);
    u16* Wqb    = (u16*)alloc((size_t)Nd*Ed*2);
    u16* Wkb    = (u16*)alloc((size_t)Nd*Ed*2);
    u16* Wvb    = (u16*)alloc((size_t)Nd*Nd*2);
    u16* WvTb   = (u16*)alloc((size_t)Nd*Nd*2);
    u16* Wo_b   = (u16*)alloc((size_t)Nd*Ed*2);
    u16* owTb   = (u16*)alloc((size_t)Ed*Ed*2);
    u16* WqqT   = (u16*)alloc((size_t)Ed*Nd*2);
    u16* WkkT   = (u16*)alloc((size_t)Ed*Nd*2);
    u16* WvvT   = (u16*)alloc((size_t)Ed*Nd*2);
    u16* Woo2T  = (u16*)alloc((size_t)Nd*Ed*2);
    float* bo   = (float*)alloc((size_t)Nd*4);
    u16* qb     = (u16*)alloc((size_t)Bd*Ed*2);
    u16* kb     = (u16*)alloc((size_t)Md*Ed*2);
    u16* vTb    = (u16*)alloc((size_t)Ed*Md*2);
    u16* ctxb   = (u16*)alloc((size_t)Bd*Ed*2);
    float* sume = (float*)alloc((size_t)Hd*Bd*4);
    float* rin1 = (float*)alloc((size_t)Hd*Bd*4);
    float* rin8 = (float*)alloc((size_t)Hd*Bd*4);
    float* part = (float*)alloc((size_t)NSL*Bd*Ed*4);   // 16 MB ctx partials
    if (off > ws_size) return;

    hipMemsetAsync(sume, 0, (size_t)Hd*Bd*4, stream);

    // conversions
    cvt_copy_k<<<Bd*Nd/1024, 256, 0, stream>>>(x, xb, out_x, Bd*Nd);
    cvt_bf16_k<<<Md*Nd/1024, 256, 0, stream>>>(Xc, Xb, Md*Nd);
    cvt_bf16_k<<<Ed*Ed/1024, 256, 0, stream>>>(qw, qwb, Ed*Ed);
    cvt_bf16_k<<<Ed*Ed/1024, 256, 0, stream>>>(kw, kwb, Ed*Ed);
    cvt_bf16_k<<<Ed*Nd/1024, 256, 0, stream>>>(vw, vwb, Ed*Nd);
    cvt_bf16_k<<<Nd*Ed/1024, 256, 0, stream>>>(Wq, Wqb, Nd*Ed);
    cvt_bf16_k<<<Nd*Ed/1024, 256, 0, stream>>>(Wk, Wkb, Nd*Ed);
    cvt_bf16_k<<<Nd*Nd/1024, 256, 0, stream>>>(Wv, Wvb, Nd*Nd);
    cvt_bf16_k<<<Nd*Ed/1024, 256, 0, stream>>>(Wo, Wo_b, Nd*Ed);
    tcvt_k<<<dim3(Nd/32, Nd/32), 256, 0, stream>>>(Wv, WvTb, Nd, Nd);   // W_v_w^T
    tcvt_k<<<dim3(Ed/32, Ed/32), 256, 0, stream>>>(ow, owTb, Ed, Ed);   // out_w^T
    gemv_bo_k<<<Nd/4, 256, 0, stream>>>(Wo, ob, Wob, bo);

    // weight combines (bf16 out)
    gemm_bt<0,0><<<dim3(Nd/128, Ed/128), 256, 0, stream>>>(qwb, Wqb, WqqT, nullptr, Ed, Nd, Ed, 0.125f);
    gemm_bt<0,0><<<dim3(Nd/128, Ed/128), 256, 0, stream>>>(kwb, Wkb, WkkT, nullptr, Ed, Nd, Ed, 1.f);
    gemm_bt<0,0><<<dim3(Nd/128, Ed/128), 256, 0, stream>>>(vwb, Wvb, WvvT, nullptr, Ed, Nd, Nd, 1.f);
    gemm_bt<0,0><<<dim3(Ed/128, Nd/128), 256, 0, stream>>>(Wo_b, owTb, Woo2T, nullptr, Nd, Ed, Ed, 1.f);

    // main projections
    gemm_bt<0,1><<<dim3(Nd/128, Md/128), 256, 0, stream>>>(Xb, WvTb, out_V, nullptr, Md, Nd, Nd, 1.f); // V (f32 out)
    gemm_bt<1,0><<<dim3(Ed/128, Bd/128), 256, 0, stream>>>(xb, WqqT, qb, bq, Bd, Ed, Nd, 1.f);          // q
    gemm_bt<1,0><<<dim3(Ed/128, Md/128), 256, 0, stream>>>(Xb, WkkT, kb, bk, Md, Ed, Nd, 1.f);          // k
    gemm_bt<2,0><<<dim3(Md/128, Ed/128), 256, 0, stream>>>(WvvT, Xb, vTb, bv, Ed, Md, Nd, 1.f);         // vT (row bias)

    // attention
    attn_sc<<<512, 256, 0, stream>>>(qb, kb, vTb, sume, part);
    rinv_k<<<Hd*Bd/256, 256, 0, stream>>>(sume, rin1, rin8);
    attn_f<<<dim3(Md/128, Bd/128), 256, 0, stream>>>(qb, kb, rin8, out_f);
    ctx_reduce_k<<<Bd*Ed/1024, 256, 0, stream>>>(part, rin1, ctxb);

    // epilogue
    gemm_bt<1,1><<<dim3(Nd/128, Bd/128), 256, 0, stream>>>(ctxb, Woo2T, out_xhat, bo, Bd, Nd, Ed, 1.f);
}